// Round 5
// baseline (35.001 us; speedup 1.0000x reference)
//
#include <hip/hip_runtime.h>

// out[b,t,n,:] = R(dof[b,t]) @ X[b,t,n,:] + T(dof[b,t])
// R = I + A K + B K^2, V = I + B K + C K^2, T = V v, K^2 = w w^T - |w|^2 I.
//
// Wave-synchronous version: each wave owns a private 3KB LDS region
// (192 float4 = 256 points) and never shares -> NO __syncthreads.
// Cross-lane exchange relies on per-wave in-order DS pipe + compiler
// ordering fences (wave_barrier, zero runtime cost).
// All global traffic is dense unit-stride float4.

typedef float f4 __attribute__((ext_vector_type(4)));

#define TPB 256   // 4 waves/block, each independent

__global__ __launch_bounds__(TPB) void se3_apply_kernel(
    const f4* __restrict__ X4,
    const float* __restrict__ dof,
    f4* __restrict__ O4,
    int wps)      // waves per (b,t) slice = NP/256
{
    __shared__ f4 lds[768];                 // 4 waves * 192 f4 (3KB each)

    const int wid  = (int)threadIdx.x >> 6;
    const int lane = (int)threadIdx.x & 63;
    const int gw   = (int)blockIdx.x * 4 + wid;     // global wave id
    const int bt   = gw / wps;
    const int base4 = gw * 192;                     // f4 index of this wave's chunk

    f4* w = lds + wid * 192;

    // ---- dense staging loads (issue first to hide latency) ----
    const f4 g0 = X4[base4 + lane];
    const f4 g1 = X4[base4 +  64 + lane];
    const f4 g2 = X4[base4 + 128 + lane];

    // ---- per-thread R,T (wave-uniform; no divergence, no broadcast) ----
    const float* d = dof + bt * 6;
    const float vx = d[0], vy = d[1], vz = d[2];
    const float wx = d[3], wy = d[4], wz = d[5];
    const float th2 = wx*wx + wy*wy + wz*wz;
    const float th  = sqrtf(th2);
    float A, Bc, C;
    if (th < 1e-4f) {
        A  = 1.0f - th2 * (1.0f/6.0f);
        Bc = 0.5f - th2 * (1.0f/24.0f);
        C  = (1.0f/6.0f) - th2 * (1.0f/120.0f);
    } else {
        const float s = sinf(th);
        const float c = cosf(th);
        A  = s / th;
        Bc = (1.0f - c) / th2;
        C  = (th - s) / (th2 * th);
    }
    const float r00 = 1.0f + Bc*(wx*wx - th2);
    const float r01 = Bc*wx*wy - A*wz;
    const float r02 = Bc*wx*wz + A*wy;
    const float r10 = Bc*wy*wx + A*wz;
    const float r11 = 1.0f + Bc*(wy*wy - th2);
    const float r12 = Bc*wy*wz - A*wx;
    const float r20 = Bc*wz*wx - A*wy;
    const float r21 = Bc*wz*wy + A*wx;
    const float r22 = 1.0f + Bc*(wz*wz - th2);
    const float q00 = 1.0f + C*(wx*wx - th2);
    const float q01 = C*wx*wy - Bc*wz;
    const float q02 = C*wx*wz + Bc*wy;
    const float q10 = C*wy*wx + Bc*wz;
    const float q11 = 1.0f + C*(wy*wy - th2);
    const float q12 = C*wy*wz - Bc*wx;
    const float q20 = C*wz*wx - Bc*wy;
    const float q21 = C*wz*wy + Bc*wx;
    const float q22 = 1.0f + C*(wz*wz - th2);
    const float Tx = q00*vx + q01*vy + q02*vz;
    const float Ty = q10*vx + q11*vy + q12*vz;
    const float Tz = q20*vx + q21*vy + q22*vz;

    // ---- in-wave transpose: dense f4 -> 4 consecutive points/lane ----
    w[lane]       = g0;
    w[64 + lane]  = g1;
    w[128 + lane] = g2;
    __builtin_amdgcn_wave_barrier();
    const f4 a = w[3*lane];
    const f4 b = w[3*lane + 1];
    const f4 c = w[3*lane + 2];
    __builtin_amdgcn_wave_barrier();

    f4 oa, ob, oc;
    {
        const float x = a.x, y = a.y, z = a.z;
        oa.x = fmaf(r00,x, fmaf(r01,y, fmaf(r02,z, Tx)));
        oa.y = fmaf(r10,x, fmaf(r11,y, fmaf(r12,z, Ty)));
        oa.z = fmaf(r20,x, fmaf(r21,y, fmaf(r22,z, Tz)));
    }
    {
        const float x = a.w, y = b.x, z = b.y;
        oa.w = fmaf(r00,x, fmaf(r01,y, fmaf(r02,z, Tx)));
        ob.x = fmaf(r10,x, fmaf(r11,y, fmaf(r12,z, Ty)));
        ob.y = fmaf(r20,x, fmaf(r21,y, fmaf(r22,z, Tz)));
    }
    {
        const float x = b.z, y = b.w, z = c.x;
        ob.z = fmaf(r00,x, fmaf(r01,y, fmaf(r02,z, Tx)));
        ob.w = fmaf(r10,x, fmaf(r11,y, fmaf(r12,z, Ty)));
        oc.x = fmaf(r20,x, fmaf(r21,y, fmaf(r22,z, Tz)));
    }
    {
        const float x = c.y, y = c.z, z = c.w;
        oc.y = fmaf(r00,x, fmaf(r01,y, fmaf(r02,z, Tx)));
        oc.z = fmaf(r10,x, fmaf(r11,y, fmaf(r12,z, Ty)));
        oc.w = fmaf(r20,x, fmaf(r21,y, fmaf(r22,z, Tz)));
    }

    // ---- in-wave transpose back: points -> dense f4, then drain ----
    w[3*lane]     = oa;
    w[3*lane + 1] = ob;
    w[3*lane + 2] = oc;
    __builtin_amdgcn_wave_barrier();
    O4[base4 + lane]       = w[lane];
    O4[base4 +  64 + lane] = w[64 + lane];
    O4[base4 + 128 + lane] = w[128 + lane];
}

extern "C" void kernel_launch(void* const* d_in, const int* in_sizes, int n_in,
                              void* d_out, int out_size, void* d_ws, size_t ws_size,
                              hipStream_t stream) {
    const float* X   = (const float*)d_in[0];   // (B, NT, NP, 3) f32
    const float* dof = (const float*)d_in[1];   // (B, NT, 6) f32
    float* out = (float*)d_out;                 // (B, NT, NP, 3) f32

    const int BT = in_sizes[1] / 6;             // B*NT = 1024
    const int NP = in_sizes[0] / (BT * 3);      // 8192
    const int wps = NP / 256;                   // waves per slice = 32
    const int total_waves = BT * wps;           // 32768
    const int blocks = total_waves / 4;         // 8192

    se3_apply_kernel<<<dim3(blocks), dim3(TPB), 0, stream>>>(
        (const f4*)X, dof, (f4*)out, wps);
}